// Round 1
// baseline (195.941 us; speedup 1.0000x reference)
//
#include <hip/hip_runtime.h>
#include <math.h>

#define HW 48
#define NPOS 2304      // 48*48
#define CCH 256
#define TILE 64
#define KC 16

// ---------------- P = lr^T * ref pixel correlation GEMM -------------------
// P[lp][rp] = sum_c lr[c*2304+lp] * ref[c*2304+rp]
__global__ __launch_bounds__(256) void gemm_p_kernel(const float* __restrict__ lr,
                                                     const float* __restrict__ ref,
                                                     float* __restrict__ P) {
    __shared__ float As[KC][TILE];
    __shared__ float Bs[KC][TILE];
    const int t  = threadIdx.x;
    const int tx = t & 15, ty = t >> 4;
    const int lp0 = blockIdx.y * TILE, rp0 = blockIdx.x * TILE;
    const int lrow = t >> 4;         // chunk row 0..15
    const int lcol = (t & 15) << 2;  // 0,4,...,60
    float acc[4][4] = {};
    for (int c0 = 0; c0 < CCH; c0 += KC) {
        float4 a4 = *(const float4*)(lr  + (size_t)(c0 + lrow) * NPOS + lp0 + lcol);
        float4 b4 = *(const float4*)(ref + (size_t)(c0 + lrow) * NPOS + rp0 + lcol);
        __syncthreads();
        *(float4*)&As[lrow][lcol] = a4;
        *(float4*)&Bs[lrow][lcol] = b4;
        __syncthreads();
#pragma unroll
        for (int kk = 0; kk < KC; ++kk) {
            float4 av = *(const float4*)&As[kk][ty << 2];
            float4 bv = *(const float4*)&Bs[kk][tx << 2];
            const float* ap = &av.x;
            const float* bp = &bv.x;
#pragma unroll
            for (int i = 0; i < 4; ++i)
#pragma unroll
                for (int j = 0; j < 4; ++j)
                    acc[i][j] = fmaf(ap[i], bp[j], acc[i][j]);
        }
    }
#pragma unroll
    for (int i = 0; i < 4; ++i) {
        float4 v = make_float4(acc[i][0], acc[i][1], acc[i][2], acc[i][3]);
        *(float4*)(P + (size_t)(lp0 + (ty << 2) + i) * NPOS + rp0 + (tx << 2)) = v;
    }
}

// ---------------- per-pixel sum of squares ---------------------------------
__global__ void ss_kernel(const float* __restrict__ img, float* __restrict__ SS) {
    int p = blockIdx.x * blockDim.x + threadIdx.x;
    if (p >= NPOS) return;
    float s = 0.f;
    for (int c = 0; c < CCH; ++c) {
        float v = img[(size_t)c * NPOS + p];
        s = fmaf(v, v, s);
    }
    SS[p] = s;
}

// ---------------- 3x3 stencil -> 1/max(norm,eps) ---------------------------
__global__ void invnorm_kernel(const float* __restrict__ SS, float* __restrict__ inv) {
    int p = blockIdx.x * blockDim.x + threadIdx.x;
    if (p >= NPOS) return;
    int y = p / HW, x = p % HW;
    float s = 0.f;
    for (int di = -1; di <= 1; ++di) {
        int yy = y + di;
        if ((unsigned)yy >= HW) continue;
        for (int dj = -1; dj <= 1; ++dj) {
            int xx = x + dj;
            if ((unsigned)xx >= HW) continue;
            s += SS[yy * HW + xx];
        }
    }
    inv[p] = 1.f / fmaxf(sqrtf(s), 1e-12f);
}

// ---------------- fused R-reconstruction + max/argmax over r ---------------
// R[l,r] = (sum_{di,dj valid} P[(yl+di)*48+xl+dj][(yr+di)*48+xr+dj]) * inr[r]
__global__ __launch_bounds__(256) void maxarg_kernel(const float* __restrict__ P,
                                                     const float* __restrict__ inr,
                                                     const float* __restrict__ inl,
                                                     float* __restrict__ S,
                                                     int* __restrict__ arg) {
    const int l  = blockIdx.x;
    const int yl = l / HW, xl = l % HW;
    const int t  = threadIdx.x;
    float best = -1e30f;
    int bestr = 0;
    for (int r = t; r < NPOS; r += 256) {
        int yr = r / HW, xr = r % HW;
        float acc = 0.f;
#pragma unroll
        for (int di = -1; di <= 1; ++di) {
            int ylp = yl + di, yrp = yr + di;
            if ((unsigned)ylp >= HW || (unsigned)yrp >= HW) continue;
#pragma unroll
            for (int dj = -1; dj <= 1; ++dj) {
                int xlp = xl + dj, xrp = xr + dj;
                if ((unsigned)xlp >= HW || (unsigned)xrp >= HW) continue;
                acc += P[(size_t)(ylp * HW + xlp) * NPOS + (yrp * HW + xrp)];
            }
        }
        float val = acc * inr[r];
        if (val > best) { best = val; bestr = r; }   // strict > keeps first max
    }
    __shared__ float bv[256];
    __shared__ int   br[256];
    bv[t] = best; br[t] = bestr;
    __syncthreads();
    for (int s2 = 128; s2 > 0; s2 >>= 1) {
        if (t < s2) {
            float v2 = bv[t + s2]; int r2 = br[t + s2];
            if (v2 > bv[t] || (v2 == bv[t] && r2 < br[t])) { bv[t] = v2; br[t] = r2; }
        }
        __syncthreads();
    }
    if (t == 0) {
        S[l]   = bv[0] * inl[l];
        arg[l] = br[0];
    }
}

// ---------------- gather+fold for one pyramid level ------------------------
// out[c,y,x] = (1/9) * sum over (oy,ox,di,dj) with s*oy+di=y+pad, s*ox+dj=x+pad
//              of ref[c, s*ry+di-pad, s*rx+dj-pad], (ry,rx)=pos(arg[oy*48+ox])
template <int K, int S, int PAD, int C, int H>
__global__ __launch_bounds__(256) void gather_fold_kernel(const float* __restrict__ ref,
                                                          const int* __restrict__ arg,
                                                          float* __restrict__ out) {
    int idx = blockIdx.x * 256 + threadIdx.x;
    const int total = C * H * H;
    if (idx >= total) return;
    int x = idx % H;
    int y = (idx / H) % H;
    int c = idx / (H * H);
    int ty_ = (y + PAD) / S;
    int tx_ = (x + PAD) / S;
    float acc = 0.f;
#pragma unroll
    for (int a = 0; a < 3; ++a) {
        int oy = ty_ - a;
        if ((unsigned)oy >= HW) continue;
        int di = y + PAD - S * oy;   // in [0,K) by construction (K == 3*S)
#pragma unroll
        for (int b = 0; b < 3; ++b) {
            int ox = tx_ - b;
            if ((unsigned)ox >= HW) continue;
            int dj = x + PAD - S * ox;
            int ar = arg[oy * HW + ox];
            int ry = ar / HW, rx = ar % HW;
            int yy = S * ry + di - PAD;
            int xx = S * rx + dj - PAD;
            if ((unsigned)yy < H && (unsigned)xx < H)
                acc += ref[((size_t)c * H + yy) * H + xx];
        }
    }
    out[idx] = acc * (1.f / 9.f);
}

extern "C" void kernel_launch(void* const* d_in, const int* in_sizes, int n_in,
                              void* d_out, int out_size, void* d_ws, size_t ws_size,
                              hipStream_t stream) {
    const float* lrsr  = (const float*)d_in[0];  // (1,256,48,48)
    const float* refsr = (const float*)d_in[1];  // (1,256,48,48)
    const float* ref1  = (const float*)d_in[2];  // (1,64,192,192)
    const float* ref2  = (const float*)d_in[3];  // (1,128,96,96)
    const float* ref3  = (const float*)d_in[4];  // (1,256,48,48)

    float* out = (float*)d_out;
    float* S   = out;                         // 2304
    float* T3  = S  + NPOS;                   // 256*48*48   = 589824
    float* T2  = T3 + 256 * 48 * 48;          // 128*96*96   = 1179648
    float* T1  = T2 + 128 * 96 * 96;          // 64*192*192  = 2359296

    float* P     = (float*)d_ws;                  // 2304*2304 f32 = 21.2 MB
    float* SStmp = P + (size_t)NPOS * NPOS;       // 2304
    float* inr   = SStmp + NPOS;                  // 2304
    float* inl   = inr + NPOS;                    // 2304
    int*   arg   = (int*)(inl + NPOS);            // 2304

    // norms (tiny)
    ss_kernel<<<(NPOS + 255) / 256, 256, 0, stream>>>(refsr, SStmp);
    invnorm_kernel<<<(NPOS + 255) / 256, 256, 0, stream>>>(SStmp, inr);
    ss_kernel<<<(NPOS + 255) / 256, 256, 0, stream>>>(lrsr, SStmp);
    invnorm_kernel<<<(NPOS + 255) / 256, 256, 0, stream>>>(SStmp, inl);

    // pixel correlation GEMM
    dim3 grid(NPOS / TILE, NPOS / TILE);
    gemm_p_kernel<<<grid, 256, 0, stream>>>(lrsr, refsr, P);

    // fused R reconstruction + max/argmax (writes S and arg)
    maxarg_kernel<<<NPOS, 256, 0, stream>>>(P, inr, inl, S, arg);

    // gather+fold transfers
    gather_fold_kernel<3, 1, 1, 256, 48><<<(256 * 48 * 48 + 255) / 256, 256, 0, stream>>>(ref3, arg, T3);
    gather_fold_kernel<6, 2, 2, 128, 96><<<(128 * 96 * 96 + 255) / 256, 256, 0, stream>>>(ref2, arg, T2);
    gather_fold_kernel<12, 4, 4, 64, 192><<<(64 * 192 * 192 + 255) / 256, 256, 0, stream>>>(ref1, arg, T1);
}

// Round 2
// 143.114 us; speedup vs baseline: 1.3691x; 1.3691x over previous
//
#include <hip/hip_runtime.h>
#include <math.h>

#define HW 48
#define NPOS 2304      // 48*48
#define CCH 256
#define PCOLS 2500     // padded 50x50 grid per row
#define KC 16
#define TM 128
#define TN 64

// ---------------- per-pixel sum of squares (both images, channel-parallel) --
__global__ __launch_bounds__(256) void ss2_kernel(const float* __restrict__ a,
                                                  const float* __restrict__ b,
                                                  float* __restrict__ SS2) {
    const float* img = blockIdx.y ? b : a;
    const int t = threadIdx.x;
    const int px = t & 63, cg = t >> 6;       // 64 pixels x 4 channel groups
    const int p = blockIdx.x * 64 + px;
    const float* base = img + (size_t)cg * 64 * NPOS + p;
    float s = 0.f;
#pragma unroll 4
    for (int cc = 0; cc < 64; ++cc) {
        float v = base[(size_t)cc * NPOS];
        s = fmaf(v, v, s);
    }
    __shared__ float red[4][64];
    red[cg][px] = s;
    __syncthreads();
    if (cg == 0)
        SS2[blockIdx.y * NPOS + p] = red[0][px] + red[1][px] + red[2][px] + red[3][px];
}

// ---------------- 3x3 stencil -> 1/max(norm,eps), both images ---------------
__global__ __launch_bounds__(256) void invnorm2_kernel(const float* __restrict__ SS2,
                                                       float* __restrict__ inv2) {
    const int p = blockIdx.x * 256 + threadIdx.x;
    const float* SS = SS2 + blockIdx.y * NPOS;
    const int y = p / HW, x = p % HW;
    float s = 0.f;
#pragma unroll
    for (int di = -1; di <= 1; ++di) {
        int yy = y + di;
        if ((unsigned)yy >= HW) continue;
#pragma unroll
        for (int dj = -1; dj <= 1; ++dj) {
            int xx = x + dj;
            if ((unsigned)xx >= HW) continue;
            s += SS[yy * HW + xx];
        }
    }
    inv2[blockIdx.y * NPOS + p] = 1.f / fmaxf(sqrtf(s), 1e-12f);
}

// ---------------- zero the 196 padded-border cells of each P row ------------
__global__ void zero_border_kernel(float* __restrict__ P) {
    int idx = blockIdx.x * 256 + threadIdx.x;
    if (idx >= NPOS * 196) return;
    int row = idx / 196, b = idx - row * 196;
    int pc;
    if (b < 50)       pc = b;                       // pad-row 0
    else if (b < 100) pc = 2450 + (b - 50);         // pad-row 49
    else {                                          // pad-cols 0 and 49, rows 1..48
        int i = b - 100;
        int rr = 1 + (i >> 1);
        pc = rr * 50 + ((i & 1) ? 49 : 0);
    }
    P[(size_t)row * PCOLS + pc] = 0.f;
}

// ---------------- P = lr^T * ref pixel correlation GEMM (padded write) ------
__global__ __launch_bounds__(256) void gemm_p_kernel(const float* __restrict__ lr,
                                                     const float* __restrict__ ref,
                                                     float* __restrict__ P) {
    __shared__ float As[KC][TM];
    __shared__ float Bs[KC][TN];
    const int t  = threadIdx.x;
    const int tx = t & 15, ty = t >> 4;
    const int lp0 = blockIdx.y * TM, rp0 = blockIdx.x * TN;
    // A staging: 128x16 = 512 float4, 2 per thread
    const int ac0 = t >> 5,        acol0 = (t & 31) << 2;
    const int ac1 = (t + 256) >> 5, acol1 = acol0;
    // B staging: 64x16 = 256 float4, 1 per thread
    const int bc = t >> 4, bcol = (t & 15) << 2;
    float acc[8][4] = {};
    for (int c0 = 0; c0 < CCH; c0 += KC) {
        float4 a0 = *(const float4*)(lr  + (size_t)(c0 + ac0) * NPOS + lp0 + acol0);
        float4 a1 = *(const float4*)(lr  + (size_t)(c0 + ac1) * NPOS + lp0 + acol1);
        float4 b0 = *(const float4*)(ref + (size_t)(c0 + bc)  * NPOS + rp0 + bcol);
        __syncthreads();
        *(float4*)&As[ac0][acol0] = a0;
        *(float4*)&As[ac1][acol1] = a1;
        *(float4*)&Bs[bc][bcol]   = b0;
        __syncthreads();
#pragma unroll
        for (int kk = 0; kk < KC; ++kk) {
            float4 aA = *(const float4*)&As[kk][ty * 8];
            float4 aB = *(const float4*)&As[kk][ty * 8 + 4];
            float4 bb = *(const float4*)&Bs[kk][tx * 4];
            const float av[8] = {aA.x, aA.y, aA.z, aA.w, aB.x, aB.y, aB.z, aB.w};
            const float bv[4] = {bb.x, bb.y, bb.z, bb.w};
#pragma unroll
            for (int i = 0; i < 8; ++i)
#pragma unroll
                for (int j = 0; j < 4; ++j)
                    acc[i][j] = fmaf(av[i], bv[j], acc[i][j]);
        }
    }
    // write into padded layout: col -> (col/48)*50 + col%48 + 51
    const int col0 = rp0 + tx * 4;
    const int pc0  = (col0 / 48) * 50 + (col0 % 48) + 51;
#pragma unroll
    for (int i = 0; i < 8; ++i) {
        const int m = lp0 + ty * 8 + i;
        float4 v = make_float4(acc[i][0], acc[i][1], acc[i][2], acc[i][3]);
        __builtin_memcpy(P + (size_t)m * PCOLS + pc0, &v, 16);
    }
}

// ---------------- fused R-reconstruction + max/argmax over r ----------------
// Padded-P: no r-side masks; l-side validity is block-uniform.
__global__ __launch_bounds__(192) void maxarg_kernel(const float* __restrict__ P,
                                                     const float* __restrict__ inr,
                                                     const float* __restrict__ inl,
                                                     float* __restrict__ S,
                                                     int* __restrict__ arg) {
    const int l  = blockIdx.x;
    const int yl = l / HW, xl = l % HW;
    const int t  = threadIdx.x;

    bool vmask[9];
    const float* bp[9];
#pragma unroll
    for (int d = 0; d < 9; ++d) {
        const int di = d / 3 - 1, dj = d % 3 - 1;
        vmask[d] = ((unsigned)(yl + di) < HW) && ((unsigned)(xl + dj) < HW);
        bp[d] = P + (ptrdiff_t)(l + di * HW + dj) * PCOLS + (di * 50 + dj);
    }

    float best = -1e30f;
    int bestr = 0;
#pragma unroll
    for (int vv = 0; vv < 3; ++vv) {
        const int v   = t + vv * 192;          // vec id 0..575
        const int yr  = v / 12;
        const int xr4 = (v - yr * 12) << 2;
        const int q0  = yr * 50 + xr4 + 51;    // padded position of (yr, xr4)
        const int r0  = yr * HW + xr4;
        float4 a = make_float4(0.f, 0.f, 0.f, 0.f);
#pragma unroll
        for (int d = 0; d < 9; ++d) {
            if (vmask[d]) {
                float4 x;
                __builtin_memcpy(&x, bp[d] + q0, 16);   // dword-aligned vec load
                a.x += x.x; a.y += x.y; a.z += x.z; a.w += x.w;
            }
        }
        const float4 w = *(const float4*)(inr + r0);
        const float vals[4] = {a.x * w.x, a.y * w.y, a.z * w.z, a.w * w.w};
#pragma unroll
        for (int k = 0; k < 4; ++k)
            if (vals[k] > best) { best = vals[k]; bestr = r0 + k; }
    }

    __shared__ float bv[256];
    __shared__ int   br[256];
    bv[t] = best; br[t] = bestr;
    if (t < 64) { bv[192 + t] = -1e30f; br[192 + t] = 0; }
    __syncthreads();
    for (int s2 = 128; s2 > 0; s2 >>= 1) {
        if (t < s2) {
            float v2 = bv[t + s2]; int r2 = br[t + s2];
            if (v2 > bv[t] || (v2 == bv[t] && r2 < br[t])) { bv[t] = v2; br[t] = r2; }
        }
        __syncthreads();
    }
    if (t == 0) {
        S[l]   = bv[0] * inl[l];
        arg[l] = br[0];
    }
}

// ---------------- gather+fold: offsets hoisted out of the channel loop ------
template <int S_, int PAD, int C, int H, int CH>
__global__ __launch_bounds__(128) void gather_fold_kernel(const float* __restrict__ ref,
                                                          const int* __restrict__ arg,
                                                          float* __restrict__ out) {
    const int px = blockIdx.x * 128 + threadIdx.x;
    const int x = px % H, y = px / H;
    const int ty_ = (y + PAD) / S_;
    const int tx_ = (x + PAD) / S_;
    int   off[9];
    float w[9];
#pragma unroll
    for (int a = 0; a < 3; ++a) {
        const int oy = ty_ - a;
        const int di = y + PAD - S_ * oy;     // in [0, 3*S_) by construction
#pragma unroll
        for (int b = 0; b < 3; ++b) {
            const int ox = tx_ - b;
            const int dj = x + PAD - S_ * ox;
            const int k = a * 3 + b;
            off[k] = 0; w[k] = 0.f;
            if ((unsigned)oy < HW && (unsigned)ox < HW) {
                const int ar = arg[oy * HW + ox];
                const int ry = ar / HW, rx = ar % HW;
                const int yy = S_ * ry + di - PAD;
                const int xx = S_ * rx + dj - PAD;
                if ((unsigned)yy < H && (unsigned)xx < H) {
                    off[k] = yy * H + xx;
                    w[k]   = 1.f / 9.f;
                }
            }
        }
    }
    const int c0 = blockIdx.y * CH;
#pragma unroll
    for (int cc = 0; cc < CH; ++cc) {
        const float* bp2 = ref + (size_t)(c0 + cc) * (H * H);
        float acc = 0.f;
#pragma unroll
        for (int k = 0; k < 9; ++k)
            acc = fmaf(w[k], bp2[off[k]], acc);
        out[(size_t)(c0 + cc) * (H * H) + px] = acc;
    }
}

extern "C" void kernel_launch(void* const* d_in, const int* in_sizes, int n_in,
                              void* d_out, int out_size, void* d_ws, size_t ws_size,
                              hipStream_t stream) {
    const float* lrsr  = (const float*)d_in[0];  // (1,256,48,48)
    const float* refsr = (const float*)d_in[1];  // (1,256,48,48)
    const float* ref1  = (const float*)d_in[2];  // (1,64,192,192)
    const float* ref2  = (const float*)d_in[3];  // (1,128,96,96)
    const float* ref3  = (const float*)d_in[4];  // (1,256,48,48)

    float* out = (float*)d_out;
    float* S   = out;                         // 2304
    float* T3  = S  + NPOS;                   // 256*48*48
    float* T2  = T3 + 256 * 48 * 48;          // 128*96*96
    float* T1  = T2 + 128 * 96 * 96;          // 64*192*192

    float* P    = (float*)d_ws;                       // 2304*2500 f32 = 23.04 MB
    float* SS2  = P + (size_t)NPOS * PCOLS;           // 2*2304
    float* inv2 = SS2 + 2 * NPOS;                     // 2*2304 (inl, inr)
    int*   arg  = (int*)(inv2 + 2 * NPOS);            // 2304
    float* inl  = inv2;
    float* inr  = inv2 + NPOS;

    // norms
    ss2_kernel<<<dim3(36, 2), 256, 0, stream>>>(lrsr, refsr, SS2);
    invnorm2_kernel<<<dim3(9, 2), 256, 0, stream>>>(SS2, inv2);

    // padded-P border zeros + pixel correlation GEMM
    zero_border_kernel<<<(NPOS * 196 + 255) / 256, 256, 0, stream>>>(P);
    gemm_p_kernel<<<dim3(NPOS / TN, NPOS / TM), 256, 0, stream>>>(lrsr, refsr, P);

    // fused R reconstruction + max/argmax
    maxarg_kernel<<<NPOS, 192, 0, stream>>>(P, inr, inl, S, arg);

    // gather+fold transfers (CH=8 channels per block in grid.y)
    gather_fold_kernel<1, 1, 256, 48, 8><<<dim3(2304 / 128, 256 / 8), 128, 0, stream>>>(ref3, arg, T3);
    gather_fold_kernel<2, 2, 128, 96, 8><<<dim3(9216 / 128, 128 / 8), 128, 0, stream>>>(ref2, arg, T2);
    gather_fold_kernel<4, 4, 64, 192, 8><<<dim3(36864 / 128, 64 / 8), 128, 0, stream>>>(ref1, arg, T1);
}

// Round 3
// 128.899 us; speedup vs baseline: 1.5201x; 1.1103x over previous
//
#include <hip/hip_runtime.h>
#include <hip/hip_bf16.h>
#include <math.h>

#define HW 48
#define NPOS 2304      // 48*48
#define CCH 256
#define PCOLS 2500     // padded 50x50 grid per row
#define PLANESZ (NPOS * CCH)   // 589824 elements per bf16 plane
#define KC 16
#define TM 128
#define TN 64

typedef __attribute__((ext_vector_type(8))) short short8v;
typedef __attribute__((ext_vector_type(16))) float f32x16;

// ---------------- per-pixel sum of squares (both images, channel-parallel) --
__global__ __launch_bounds__(256) void ss2_kernel(const float* __restrict__ a,
                                                  const float* __restrict__ b,
                                                  float* __restrict__ SS2) {
    const float* img = blockIdx.y ? b : a;
    const int t = threadIdx.x;
    const int px = t & 63, cg = t >> 6;       // 64 pixels x 4 channel groups
    const int p = blockIdx.x * 64 + px;
    const float* base = img + (size_t)cg * 64 * NPOS + p;
    float s = 0.f;
#pragma unroll 4
    for (int cc = 0; cc < 64; ++cc) {
        float v = base[(size_t)cc * NPOS];
        s = fmaf(v, v, s);
    }
    __shared__ float red[4][64];
    red[cg][px] = s;
    __syncthreads();
    if (cg == 0)
        SS2[blockIdx.y * NPOS + p] = red[0][px] + red[1][px] + red[2][px] + red[3][px];
}

// ---------------- 3x3 stencil -> 1/max(norm,eps), both images ---------------
__global__ __launch_bounds__(256) void invnorm2_kernel(const float* __restrict__ SS2,
                                                       float* __restrict__ inv2) {
    const int p = blockIdx.x * 256 + threadIdx.x;
    const float* SS = SS2 + blockIdx.y * NPOS;
    const int y = p / HW, x = p % HW;
    float s = 0.f;
#pragma unroll
    for (int di = -1; di <= 1; ++di) {
        int yy = y + di;
        if ((unsigned)yy >= HW) continue;
#pragma unroll
        for (int dj = -1; dj <= 1; ++dj) {
            int xx = x + dj;
            if ((unsigned)xx >= HW) continue;
            s += SS[yy * HW + xx];
        }
    }
    inv2[blockIdx.y * NPOS + p] = 1.f / fmaxf(sqrtf(s), 1e-12f);
}

// ---------------- zero the 196 padded-border cells of each P row ------------
__global__ void zero_border_kernel(float* __restrict__ P) {
    int idx = blockIdx.x * 256 + threadIdx.x;
    if (idx >= NPOS * 196) return;
    int row = idx / 196, b = idx - row * 196;
    int pc;
    if (b < 50)       pc = b;                       // pad-row 0
    else if (b < 100) pc = 2450 + (b - 50);         // pad-row 49
    else {                                          // pad-cols 0 and 49, rows 1..48
        int i = b - 100;
        int rr = 1 + (i >> 1);
        pc = rr * 50 + ((i & 1) ? 49 : 0);
    }
    P[(size_t)row * PCOLS + pc] = 0.f;
}

// ---------------- f32 -> 3-term bf16 split, fragment-native layout ----------
// planes: [img2][plane3][blk72][k16][lane64][8]  (bf16 as ushort)
// element (pos, c): pos = blk*32 + (lane&31), c = k16*16 + (lane>>5)*8 + e
__global__ __launch_bounds__(256) void split_kernel(const float* __restrict__ lr,
                                                    const float* __restrict__ ref,
                                                    ushort* __restrict__ planes) {
    const int gid = blockIdx.x * 256 + threadIdx.x;   // octet id, 73728 per image
    const int img = blockIdx.y;
    const float* src = img ? ref : lr;
    const int lane = gid & 63;
    const int k16  = (gid >> 6) & 15;
    const int blk  = gid >> 10;
    const int pos  = blk * 32 + (lane & 31);
    const int c0   = k16 * 16 + (lane >> 5) * 8;
    ushort h8[8], m8[8], l8[8];
#pragma unroll
    for (int e = 0; e < 8; ++e) {
        float a = src[(size_t)(c0 + e) * NPOS + pos];
        __hip_bfloat16 hb = __float2bfloat16(a);
        float hf = __bfloat162float(hb);
        float r1 = a - hf;
        __hip_bfloat16 mb = __float2bfloat16(r1);
        float mf = __bfloat162float(mb);
        __hip_bfloat16 lb = __float2bfloat16(r1 - mf);
        h8[e] = *(ushort*)&hb;
        m8[e] = *(ushort*)&mb;
        l8[e] = *(ushort*)&lb;
    }
    ushort* ph = planes + (size_t)(img * 3 + 0) * PLANESZ + (size_t)gid * 8;
    ushort* pm = planes + (size_t)(img * 3 + 1) * PLANESZ + (size_t)gid * 8;
    ushort* pl = planes + (size_t)(img * 3 + 2) * PLANESZ + (size_t)gid * 8;
#pragma unroll
    for (int e = 0; e < 8; ++e) { ph[e] = h8[e]; pm[e] = m8[e]; pl[e] = l8[e]; }
}

// ---------------- MFMA correlation GEMM (3-term split, 6 products) ----------
// Block: 4 waves stacked on M. Block tile 128M x 64N; wave tile 32M x 64N.
__global__ __launch_bounds__(256, 2) void gemm_mfma_kernel(const ushort* __restrict__ planes,
                                                           float* __restrict__ P) {
    const int t = threadIdx.x, lane = t & 63, w = t >> 6;
    const int nblk0 = blockIdx.x * 2;           // two 32-col fragments
    const int ablk  = blockIdx.y * 4 + w;       // wave's 32-row block

    const ushort* baseA  = planes + ((size_t)(ablk * 16) * 64 + lane) * 8;
    const ushort* baseB0 = planes + (size_t)3 * PLANESZ + ((size_t)(nblk0 * 16) * 64 + lane) * 8;
    const ushort* baseB1 = baseB0 + 16 * 64 * 8;

    f32x16 acc0 = {};
    f32x16 acc1 = {};
#pragma unroll
    for (int k = 0; k < 16; ++k) {
        const int fo = k * 512;
        short8v ah = *(const short8v*)(baseA + fo);
        short8v am = *(const short8v*)(baseA + PLANESZ + fo);
        short8v al = *(const short8v*)(baseA + 2 * PLANESZ + fo);
        short8v bh0 = *(const short8v*)(baseB0 + fo);
        short8v bm0 = *(const short8v*)(baseB0 + PLANESZ + fo);
        short8v bl0 = *(const short8v*)(baseB0 + 2 * PLANESZ + fo);
        short8v bh1 = *(const short8v*)(baseB1 + fo);
        short8v bm1 = *(const short8v*)(baseB1 + PLANESZ + fo);
        short8v bl1 = *(const short8v*)(baseB1 + 2 * PLANESZ + fo);
        acc0 = __builtin_amdgcn_mfma_f32_32x32x16_bf16(ah, bh0, acc0, 0, 0, 0);
        acc0 = __builtin_amdgcn_mfma_f32_32x32x16_bf16(ah, bm0, acc0, 0, 0, 0);
        acc0 = __builtin_amdgcn_mfma_f32_32x32x16_bf16(am, bh0, acc0, 0, 0, 0);
        acc0 = __builtin_amdgcn_mfma_f32_32x32x16_bf16(ah, bl0, acc0, 0, 0, 0);
        acc0 = __builtin_amdgcn_mfma_f32_32x32x16_bf16(al, bh0, acc0, 0, 0, 0);
        acc0 = __builtin_amdgcn_mfma_f32_32x32x16_bf16(am, bm0, acc0, 0, 0, 0);
        acc1 = __builtin_amdgcn_mfma_f32_32x32x16_bf16(ah, bh1, acc1, 0, 0, 0);
        acc1 = __builtin_amdgcn_mfma_f32_32x32x16_bf16(ah, bm1, acc1, 0, 0, 0);
        acc1 = __builtin_amdgcn_mfma_f32_32x32x16_bf16(am, bh1, acc1, 0, 0, 0);
        acc1 = __builtin_amdgcn_mfma_f32_32x32x16_bf16(ah, bl1, acc1, 0, 0, 0);
        acc1 = __builtin_amdgcn_mfma_f32_32x32x16_bf16(al, bh1, acc1, 0, 0, 0);
        acc1 = __builtin_amdgcn_mfma_f32_32x32x16_bf16(am, bm1, acc1, 0, 0, 0);
    }
    // epilogue: C/D layout col=lane&31, row=(reg&3)+8*(reg>>2)+4*(lane>>5)
    const int m0 = blockIdx.y * 128 + w * 32;
    const int half = lane >> 5;
    const int colA = nblk0 * 32 + (lane & 31);
    const int colB = colA + 32;
    const int pcA = (colA / 48) * 50 + colA % 48 + 51;
    const int pcB = (colB / 48) * 50 + colB % 48 + 51;
#pragma unroll
    for (int r = 0; r < 16; ++r) {
        const int row = (r & 3) + 8 * (r >> 2) + 4 * half;
        P[(size_t)(m0 + row) * PCOLS + pcA] = acc0[r];
        P[(size_t)(m0 + row) * PCOLS + pcB] = acc1[r];
    }
}

// ---------------- f32 fallback GEMM (if workspace too small) ----------------
__global__ __launch_bounds__(256) void gemm_p_kernel(const float* __restrict__ lr,
                                                     const float* __restrict__ ref,
                                                     float* __restrict__ P) {
    __shared__ float As[KC][TM];
    __shared__ float Bs[KC][TN];
    const int t  = threadIdx.x;
    const int tx = t & 15, ty = t >> 4;
    const int lp0 = blockIdx.y * TM, rp0 = blockIdx.x * TN;
    const int ac0 = t >> 5,        acol0 = (t & 31) << 2;
    const int ac1 = (t + 256) >> 5, acol1 = acol0;
    const int bc = t >> 4, bcol = (t & 15) << 2;
    float acc[8][4] = {};
    for (int c0 = 0; c0 < CCH; c0 += KC) {
        float4 a0 = *(const float4*)(lr  + (size_t)(c0 + ac0) * NPOS + lp0 + acol0);
        float4 a1 = *(const float4*)(lr  + (size_t)(c0 + ac1) * NPOS + lp0 + acol1);
        float4 b0 = *(const float4*)(ref + (size_t)(c0 + bc)  * NPOS + rp0 + bcol);
        __syncthreads();
        *(float4*)&As[ac0][acol0] = a0;
        *(float4*)&As[ac1][acol1] = a1;
        *(float4*)&Bs[bc][bcol]   = b0;
        __syncthreads();
#pragma unroll
        for (int kk = 0; kk < KC; ++kk) {
            float4 aA = *(const float4*)&As[kk][ty * 8];
            float4 aB = *(const float4*)&As[kk][ty * 8 + 4];
            float4 bb = *(const float4*)&Bs[kk][tx * 4];
            const float av[8] = {aA.x, aA.y, aA.z, aA.w, aB.x, aB.y, aB.z, aB.w};
            const float bv[4] = {bb.x, bb.y, bb.z, bb.w};
#pragma unroll
            for (int i = 0; i < 8; ++i)
#pragma unroll
                for (int j = 0; j < 4; ++j)
                    acc[i][j] = fmaf(av[i], bv[j], acc[i][j]);
        }
    }
    const int col0 = rp0 + tx * 4;
    const int pc0  = (col0 / 48) * 50 + (col0 % 48) + 51;
#pragma unroll
    for (int i = 0; i < 8; ++i) {
        const int m = lp0 + ty * 8 + i;
        float4 v = make_float4(acc[i][0], acc[i][1], acc[i][2], acc[i][3]);
        __builtin_memcpy(P + (size_t)m * PCOLS + pc0, &v, 16);
    }
}

// ---------------- fused R-reconstruction + max/argmax over r ----------------
__global__ __launch_bounds__(192) void maxarg_kernel(const float* __restrict__ P,
                                                     const float* __restrict__ inr,
                                                     const float* __restrict__ inl,
                                                     float* __restrict__ S,
                                                     int* __restrict__ arg) {
    const int l  = blockIdx.x;
    const int yl = l / HW, xl = l % HW;
    const int t  = threadIdx.x;

    bool vmask[9];
    const float* bp[9];
#pragma unroll
    for (int d = 0; d < 9; ++d) {
        const int di = d / 3 - 1, dj = d % 3 - 1;
        vmask[d] = ((unsigned)(yl + di) < HW) && ((unsigned)(xl + dj) < HW);
        bp[d] = P + (ptrdiff_t)(l + di * HW + dj) * PCOLS + (di * 50 + dj);
    }

    float best = -1e30f;
    int bestr = 0;
#pragma unroll
    for (int vv = 0; vv < 3; ++vv) {
        const int v   = t + vv * 192;          // vec id 0..575
        const int yr  = v / 12;
        const int xr4 = (v - yr * 12) << 2;
        const int q0  = yr * 50 + xr4 + 51;
        const int r0  = yr * HW + xr4;
        float4 a = make_float4(0.f, 0.f, 0.f, 0.f);
#pragma unroll
        for (int d = 0; d < 9; ++d) {
            if (vmask[d]) {
                float4 x;
                __builtin_memcpy(&x, bp[d] + q0, 16);
                a.x += x.x; a.y += x.y; a.z += x.z; a.w += x.w;
            }
        }
        const float4 w = *(const float4*)(inr + r0);
        const float vals[4] = {a.x * w.x, a.y * w.y, a.z * w.z, a.w * w.w};
#pragma unroll
        for (int k = 0; k < 4; ++k)
            if (vals[k] > best) { best = vals[k]; bestr = r0 + k; }
    }

    __shared__ float bv[256];
    __shared__ int   br[256];
    bv[t] = best; br[t] = bestr;
    if (t < 64) { bv[192 + t] = -1e30f; br[192 + t] = 0; }
    __syncthreads();
    for (int s2 = 128; s2 > 0; s2 >>= 1) {
        if (t < s2) {
            float v2 = bv[t + s2]; int r2 = br[t + s2];
            if (v2 > bv[t] || (v2 == bv[t] && r2 < br[t])) { bv[t] = v2; br[t] = r2; }
        }
        __syncthreads();
    }
    if (t == 0) {
        S[l]   = bv[0] * inl[l];
        arg[l] = br[0];
    }
}

// ---------------- gather+fold: offsets hoisted out of the channel loop ------
template <int S_, int PAD, int C, int H, int CH>
__global__ __launch_bounds__(128) void gather_fold_kernel(const float* __restrict__ ref,
                                                          const int* __restrict__ arg,
                                                          float* __restrict__ out) {
    const int px = blockIdx.x * 128 + threadIdx.x;
    const int x = px % H, y = px / H;
    const int ty_ = (y + PAD) / S_;
    const int tx_ = (x + PAD) / S_;
    int   off[9];
    float w[9];
#pragma unroll
    for (int a = 0; a < 3; ++a) {
        const int oy = ty_ - a;
        const int di = y + PAD - S_ * oy;
#pragma unroll
        for (int b = 0; b < 3; ++b) {
            const int ox = tx_ - b;
            const int dj = x + PAD - S_ * ox;
            const int k = a * 3 + b;
            off[k] = 0; w[k] = 0.f;
            if ((unsigned)oy < HW && (unsigned)ox < HW) {
                const int ar = arg[oy * HW + ox];
                const int ry = ar / HW, rx = ar % HW;
                const int yy = S_ * ry + di - PAD;
                const int xx = S_ * rx + dj - PAD;
                if ((unsigned)yy < H && (unsigned)xx < H) {
                    off[k] = yy * H + xx;
                    w[k]   = 1.f / 9.f;
                }
            }
        }
    }
    const int c0 = blockIdx.y * CH;
#pragma unroll
    for (int cc = 0; cc < CH; ++cc) {
        const float* bp2 = ref + (size_t)(c0 + cc) * (H * H);
        float acc = 0.f;
#pragma unroll
        for (int k = 0; k < 9; ++k)
            acc = fmaf(w[k], bp2[off[k]], acc);
        out[(size_t)(c0 + cc) * (H * H) + px] = acc;
    }
}

extern "C" void kernel_launch(void* const* d_in, const int* in_sizes, int n_in,
                              void* d_out, int out_size, void* d_ws, size_t ws_size,
                              hipStream_t stream) {
    const float* lrsr  = (const float*)d_in[0];  // (1,256,48,48)
    const float* refsr = (const float*)d_in[1];  // (1,256,48,48)
    const float* ref1  = (const float*)d_in[2];  // (1,64,192,192)
    const float* ref2  = (const float*)d_in[3];  // (1,128,96,96)
    const float* ref3  = (const float*)d_in[4];  // (1,256,48,48)

    float* out = (float*)d_out;
    float* S   = out;                         // 2304
    float* T3  = S  + NPOS;                   // 256*48*48
    float* T2  = T3 + 256 * 48 * 48;          // 128*96*96
    float* T1  = T2 + 128 * 96 * 96;          // 64*192*192

    float*  P      = (float*)d_ws;                    // 2304*2500 f32 = 23.04 MB
    float*  SS2    = P + (size_t)NPOS * PCOLS;        // 2*2304
    float*  inv2   = SS2 + 2 * NPOS;                  // 2*2304 (inl, inr)
    int*    arg    = (int*)(inv2 + 2 * NPOS);         // 2304
    ushort* planes = (ushort*)(arg + NPOS);           // 6 * 589824 bf16 = 7.08 MB
    float*  inl    = inv2;
    float*  inr    = inv2 + NPOS;

    const size_t need = ((size_t)NPOS * PCOLS + 5 * NPOS) * 4 + (size_t)6 * PLANESZ * 2;
    const bool mfma_path = ws_size >= need;

    // norms
    ss2_kernel<<<dim3(36, 2), 256, 0, stream>>>(lrsr, refsr, SS2);
    invnorm2_kernel<<<dim3(9, 2), 256, 0, stream>>>(SS2, inv2);

    // padded-P border zeros
    zero_border_kernel<<<(NPOS * 196 + 255) / 256, 256, 0, stream>>>(P);

    // pixel correlation GEMM
    if (mfma_path) {
        split_kernel<<<dim3(288, 2), 256, 0, stream>>>(lrsr, refsr, planes);
        gemm_mfma_kernel<<<dim3(NPOS / 64, NPOS / 128), 256, 0, stream>>>(planes, P);
    } else {
        gemm_p_kernel<<<dim3(NPOS / TN, NPOS / TM), 256, 0, stream>>>(lrsr, refsr, P);
    }

    // fused R reconstruction + max/argmax
    maxarg_kernel<<<NPOS, 192, 0, stream>>>(P, inr, inl, S, arg);

    // gather+fold transfers
    gather_fold_kernel<1, 1, 256, 48, 8><<<dim3(2304 / 128, 256 / 8), 128, 0, stream>>>(ref3, arg, T3);
    gather_fold_kernel<2, 2, 128, 96, 8><<<dim3(9216 / 128, 128 / 8), 128, 0, stream>>>(ref2, arg, T2);
    gather_fold_kernel<4, 4, 64, 192, 8><<<dim3(36864 / 128, 64 / 8), 128, 0, stream>>>(ref1, arg, T1);
}